// Round 16
// baseline (436.934 us; speedup 1.0000x reference)
//
#include <hip/hip_runtime.h>
#include <hip/hip_bf16.h>

#define BB 16
#define NN 4096
#define SS 512
#define KK 32
#define CNTF 262144.0f
#define FT 256  // FPS threads per block (4 waves)
#define FP 16   // points per thread = NN/FT (8 pairs)

typedef short bf16x8 __attribute__((ext_vector_type(8)));
typedef float f32x4 __attribute__((ext_vector_type(4)));
typedef float f32x2 __attribute__((ext_vector_type(2)));

__device__ __forceinline__ unsigned short f2bf(float x) {
  __hip_bfloat16 h = __float2bfloat16(x);
  return *reinterpret_cast<unsigned short*>(&h);
}

// u64 max-combine with a DPP-permuted partner (VALU pipe, no LDS latency).
// 0xB1/0x4E/0x141/0x140 then 0x142 row_bcast15 + 0x143 row_bcast31:
// lanes 48-63 end with the full 64-lane max (validated R14/R15, output-0 exact).
#define DPP_COMBINE(kk, CTRL)                                                         \
  {                                                                                   \
    unsigned lo_ = (unsigned)(kk), hi_ = (unsigned)((kk) >> 32);                      \
    unsigned plo_ = (unsigned)__builtin_amdgcn_update_dpp(0, (int)lo_, (CTRL), 0xF, 0xF, true); \
    unsigned phi_ = (unsigned)__builtin_amdgcn_update_dpp(0, (int)hi_, (CTRL), 0xF, 0xF, true); \
    unsigned long long ok_ = ((unsigned long long)phi_ << 32) | plo_;                 \
    kk = (kk) > ok_ ? (kk) : ok_;                                                     \
  }

// ---------------- FPS: R14 structure + packed-f32 dist loop ----------------
// Dist update on point-PAIRS via v_pk ops (per-half IEEE rn; contract(off)
// keeps the exact ((dx*dx+dy*dy)+dz*dz) rounding — bit-exact validated R9).
// Pair-resolve: strict > prefers lower index on ties, then strict > across
// ascending pairs == original sequential argmax (validated R9, output-0 OK).
// Tail: 6x DPP all-VALU wave reduce, lane-63 winner write, parity 4-key
// table, float4 coord broadcast (validated R14/R15).
__global__ __launch_bounds__(FT) void k_fps(const float* __restrict__ xyz,
                                            float* __restrict__ newxyz,
                                            float* __restrict__ dout) {
  __shared__ __align__(16) float4 ps[NN];
  __shared__ __align__(16) unsigned long long sKey[2][4];
  const int b = blockIdx.x;
  const int tid = threadIdx.x;
  const int wid = tid >> 6;
  const float* px = xyz + (size_t)b * 3 * NN;
  f32x2 X[8], Y[8], Z[8], D[8];
#pragma unroll
  for (int i = 0; i < 8; i++) {
    int n0 = (2 * i) * FT + tid;
    int n1 = n0 + FT;
    float x0 = px[n0], y0 = px[NN + n0], z0 = px[2 * NN + n0];
    float x1 = px[n1], y1 = px[NN + n1], z1 = px[2 * NN + n1];
    X[i] = f32x2{x0, x1}; Y[i] = f32x2{y0, y1}; Z[i] = f32x2{z0, z1};
    D[i] = f32x2{1e10f, 1e10f};
    ps[n0] = make_float4(x0, y0, z0, 0.f);
    ps[n1] = make_float4(x1, y1, z1, 0.f);
  }
  __syncthreads();
  float cx = px[0], cy = px[NN], cz = px[2 * NN];
  float c0x = 0.f, c0y = 0.f, c0z = 0.f, c1x = 0.f, c1y = 0.f, c1z = 0.f;
  for (int s = 0;; s++) {
    bool cap = (tid == (s & 255));
    if (s < 256) {
      if (cap) { c0x = cx; c0y = cy; c0z = cz; }
    } else {
      if (cap) { c1x = cx; c1y = cy; c1z = cz; }
    }
    if (s == SS - 1) break;
    float bestd = -1.0f;
    unsigned bestn = 0u;
#pragma unroll
    for (int i = 0; i < 8; i++) {
#pragma clang fp contract(off)
      // replicate ref per half: d = ((dx*dx + dy*dy) + dz*dz), no FMA fusion
      f32x2 dx = X[i] - cx;
      f32x2 dy = Y[i] - cy;
      f32x2 dz = Z[i] - cz;
      f32x2 d = (dx * dx + dy * dy) + dz * dz;
      f32x2 dm = __builtin_elementwise_min(D[i], d);
      D[i] = dm;
      // pair resolve: strict > prefers the lower index (2i) on ties, then
      // strict > across ascending pairs == sequential argmax (R9-validated).
      bool t = dm.y > dm.x;
      float dp = t ? dm.y : dm.x;
      unsigned np = (unsigned)((2 * i + (t ? 1 : 0)) * FT + tid);
      if (dp > bestd) { bestd = dp; bestn = np; }
    }
    unsigned long long wbest =
        ((unsigned long long)__float_as_uint(bestd) << 32) | (unsigned)(~bestn);
    DPP_COMBINE(wbest, 0xB1);
    DPP_COMBINE(wbest, 0x4E);
    DPP_COMBINE(wbest, 0x141);
    DPP_COMBINE(wbest, 0x140);
    DPP_COMBINE(wbest, 0x142);
    DPP_COMBINE(wbest, 0x143);
    int p = s & 1;
    if ((tid & 63) == 63) sKey[p][wid] = wbest;
    __syncthreads();
    const ulonglong2* kp = (const ulonglong2*)&sKey[p][0];
    ulonglong2 v0 = kp[0], v1 = kp[1];
    unsigned long long ka = (v0.y > v0.x) ? v0.y : v0.x;
    unsigned long long kb = (v1.y > v1.x) ? v1.y : v1.x;
    unsigned long long km = (kb > ka) ? kb : ka;
    unsigned n = ~(unsigned)km;
    float4 c4 = ps[n];
    cx = c4.x; cy = c4.y; cz = c4.z;
  }
  {
    float* nx0 = newxyz + ((size_t)b * SS + tid) * 3;
    nx0[0] = c0x; nx0[1] = c0y; nx0[2] = c0z;
    float* nx1 = newxyz + ((size_t)b * SS + 256 + tid) * 3;
    nx1[0] = c1x; nx1[1] = c1y; nx1[2] = c1z;
    float* d0 = dout + (size_t)b * 3 * SS;
    d0[tid] = c0x;        d0[SS + tid] = c0y;        d0[2 * SS + tid] = c0z;
    d0[256 + tid] = c1x;  d0[SS + 256 + tid] = c1y;  d0[2 * SS + 256 + tid] = c1z;
  }
}

// ---------------- Ball query: one wave per center, f64 distance ----------------
__global__ __launch_bounds__(256) void k_ball(const float* __restrict__ xyz,
                                              const float* __restrict__ newxyz,
                                              int* __restrict__ gi) {
  const int lane = threadIdx.x & 63;
  const int w = threadIdx.x >> 6;
  const int idx = blockIdx.x * 4 + w;  // center id in [0, B*S)
  const int b = idx >> 9;
  const float* px = xyz + (size_t)b * 3 * NN;
  const float* c = newxyz + (size_t)idx * 3;
  const double R2 = 0.2 * 0.2;
  double cx = (double)c[0], cy = (double)c[1], cz = (double)c[2];
  double ca = cx * cx + cy * cy + cz * cz;
  int total = 0;
  int first_n = 0;
  bool found = false;
  unsigned long long lt = (1ull << lane) - 1ull;
  for (int chunk = 0; chunk < NN / 64; chunk++) {
    int n = chunk * 64 + lane;
    double x = (double)px[n], y = (double)px[NN + n], z = (double)px[2 * NN + n];
    double sb = x * x + y * y + z * z;
    double dot = cx * x + cy * y + cz * z;
    double sqr = (ca + sb) - 2.0 * dot;
    bool in = sqr <= R2;
    unsigned long long m = __ballot(in);
    if (!found && m) { first_n = chunk * 64 + __builtin_ctzll(m); found = true; }
    int rank = total + __popcll(m & lt);
    if (in && rank < KK) gi[(size_t)idx * KK + rank] = n;
    total += __popcll(m);
    if (total >= KK) break;
  }
  if (total < KK) {
    for (int slot = total + lane; slot < KK; slot += 64) gi[(size_t)idx * KK + slot] = first_n;
  }
}

// ---------------- Fused grouping + layer-1 stats (validated R15) ------------
__global__ __launch_bounds__(256) void k_group_stats(const float* __restrict__ xyz,
                                                     const float* __restrict__ pts,
                                                     const float* __restrict__ newxyz,
                                                     const int* __restrict__ gi,
                                                     const float* __restrict__ W0,
                                                     const float* __restrict__ b0,
                                                     float* __restrict__ h0,
                                                     float* __restrict__ part) {
  __shared__ float hs[256 * 6];
  __shared__ float sred[512];
  int tid = threadIdx.x;
  int base = blockIdx.x * 256;
  int m = base + tid;
  int b = m >> 14;
  int bs = m >> 5;
  int n = gi[m];
  const float* px = xyz + (size_t)b * 3 * NN;
  const float* pp = pts + (size_t)b * 3 * NN;
  const float* c = newxyz + (size_t)bs * 3;
  float f0 = px[n] - c[0];
  float f1 = px[NN + n] - c[1];
  float f2 = px[2 * NN + n] - c[2];
  float f3 = pp[n];
  float f4 = pp[NN + n];
  float f5 = pp[2 * NN + n];
  float* o = h0 + (size_t)m * 6;
  o[0] = f0; o[1] = f1; o[2] = f2; o[3] = f3; o[4] = f4; o[5] = f5;
  float* hr = hs + tid * 6;
  hr[0] = f0; hr[1] = f1; hr[2] = f2; hr[3] = f3; hr[4] = f4; hr[5] = f5;
  __syncthreads();
  int cc = tid & 63, g = tid >> 6;
  float w[6];
#pragma unroll
  for (int j = 0; j < 6; j++) w[j] = W0[cc * 6 + j];
  float bb = b0[cc];
  float s1 = 0.f, s2 = 0.f;
  for (int i = g; i < 256; i += 4) {
    float v = bb;
#pragma unroll
    for (int j = 0; j < 6; j++) v = fmaf(w[j], hs[i * 6 + j], v);
    s1 += v; s2 = fmaf(v, v, s2);
  }
  sred[tid] = s1; sred[256 + tid] = s2;
  __syncthreads();
  if (tid < 64) {
    float a = 0.f, q = 0.f;
#pragma unroll
    for (int g2 = 0; g2 < 4; g2++) { a += sred[tid + 64 * g2]; q += sred[256 + tid + 64 * g2]; }
    part[blockIdx.x * 256 + tid] = a;
    part[blockIdx.x * 256 + 128 + tid] = q;
  }
}

// ---------------- Reduce stats -> scale/shift ----------------
__global__ __launch_bounds__(256) void k_reduce(const float* __restrict__ part, int NBLK,
                                                const float* __restrict__ gamma,
                                                const float* __restrict__ beta,
                                                float* __restrict__ scale,
                                                float* __restrict__ shift) {
  __shared__ float sr[512];
  int c = blockIdx.x;
  int tid = threadIdx.x;
  float s1 = 0.f, s2 = 0.f;
  for (int nb = tid; nb < NBLK; nb += 256) {
    s1 += part[(size_t)nb * 256 + c];
    s2 += part[(size_t)nb * 256 + 128 + c];
  }
  sr[tid] = s1; sr[256 + tid] = s2;
  __syncthreads();
  for (int off = 128; off >= 1; off >>= 1) {
    if (tid < off) { sr[tid] += sr[tid + off]; sr[256 + tid] += sr[256 + tid + off]; }
    __syncthreads();
  }
  if (tid == 0) {
    float m = sr[0] / CNTF;
    float v = sr[256] / CNTF - m * m;
    float sc = gamma[c] / sqrtf(v + 1e-5f);
    scale[c] = sc;
    shift[c] = beta[c] - m * sc;
  }
}

// ---------------- Layer-2 via MFMA (validated R15) ----------
__global__ __launch_bounds__(256) void k_l2(const float* __restrict__ h0,
                                            const float* __restrict__ W0,
                                            const float* __restrict__ b0,
                                            const float* __restrict__ scale1,
                                            const float* __restrict__ shift1,
                                            const float* __restrict__ W1,
                                            const float* __restrict__ b1,
                                            __hip_bfloat16* __restrict__ l2,
                                            float* __restrict__ part) {
  __shared__ float hs[128 * 6];
  __shared__ __align__(16) unsigned short a1s[128][64];
  __shared__ __align__(16) unsigned short w1s[64][64];
  __shared__ float sst1[64][17];
  __shared__ float sst2[64][17];
  __shared__ float sb1[64];
  int tid = threadIdx.x;
  int base = blockIdx.x * 128;
  for (int t = tid; t < 768; t += 256) hs[t] = h0[(size_t)base * 6 + t];
  for (int t = tid; t < 4096; t += 256) {
    int n = t >> 6, k = t & 63;
    int kc = (k >> 3) ^ (n & 7);
    w1s[n][kc * 8 + (k & 7)] = f2bf(W1[t]);
  }
  if (tid < 64) sb1[tid] = b1[tid];
  __syncthreads();
  for (int t = tid; t < 8192; t += 256) {
    int i = t >> 6, k = t & 63;
    float v = b0[k];
#pragma unroll
    for (int j = 0; j < 6; j++) v = fmaf(W0[k * 6 + j], hs[i * 6 + j], v);
    float a = fmaxf(fmaf(scale1[k], v, shift1[k]), 0.f);
    int kc = (k >> 3) ^ (i & 7);
    a1s[i][kc * 8 + (k & 7)] = f2bf(a);
  }
  __syncthreads();
  int w = tid >> 6, l = tid & 63, lr = l & 15, lk = l >> 4;
  bf16x8 A[2][2];
#pragma unroll
  for (int mt = 0; mt < 2; mt++) {
    int row = (w * 2 + mt) * 16 + lr;
#pragma unroll
    for (int kb = 0; kb < 2; kb++) {
      int kc = (kb * 4 + lk) ^ (row & 7);
      A[mt][kb] = *(const bf16x8*)&a1s[row][kc * 8];
    }
  }
  f32x4 acc[2][4];
#pragma unroll
  for (int mt = 0; mt < 2; mt++)
#pragma unroll
    for (int nt = 0; nt < 4; nt++) acc[mt][nt] = f32x4{0.f, 0.f, 0.f, 0.f};
#pragma unroll
  for (int nt = 0; nt < 4; nt++) {
    int n = nt * 16 + lr;
    int kc0 = lk ^ (n & 7);
    int kc1 = (4 + lk) ^ (n & 7);
    bf16x8 B0 = *(const bf16x8*)&w1s[n][kc0 * 8];
    bf16x8 B1 = *(const bf16x8*)&w1s[n][kc1 * 8];
#pragma unroll
    for (int mt = 0; mt < 2; mt++) {
      acc[mt][nt] = __builtin_amdgcn_mfma_f32_16x16x32_bf16(A[mt][0], B0, acc[mt][nt], 0, 0, 0);
      acc[mt][nt] = __builtin_amdgcn_mfma_f32_16x16x32_bf16(A[mt][1], B1, acc[mt][nt], 0, 0, 0);
    }
  }
  int slot = w * 4 + lk;
#pragma unroll
  for (int nt = 0; nt < 4; nt++) {
    int cch = nt * 16 + lr;
    float bias = sb1[cch];
    float s1 = 0.f, s2 = 0.f;
#pragma unroll
    for (int mt = 0; mt < 2; mt++)
#pragma unroll
      for (int r = 0; r < 4; r++) {
        float v = acc[mt][nt][r] + bias;
        int row = (w * 2 + mt) * 16 + lk * 4 + r;  // C layout: row=(l>>4)*4+r, col=l&15
        l2[(size_t)(base + row) * 64 + cch] = __float2bfloat16(v);
        s1 += v; s2 = fmaf(v, v, s2);
      }
    sst1[cch][slot] = s1; sst2[cch][slot] = s2;
  }
  __syncthreads();
  if (tid < 64) {
    float s1 = 0.f, s2 = 0.f;
#pragma unroll
    for (int t = 0; t < 16; t++) { s1 += sst1[tid][t]; s2 += sst2[tid][t]; }
    part[blockIdx.x * 256 + tid] = s1;
    part[blockIdx.x * 256 + 128 + tid] = s2;
  }
}

// ---------------- Layer-3 single pass via MFMA (validated R11/R12) ----------
__global__ __launch_bounds__(256) void k_l3pass(const __hip_bfloat16* __restrict__ l2,
                                                const float* __restrict__ scale2,
                                                const float* __restrict__ shift2,
                                                const float* __restrict__ W2,
                                                const float* __restrict__ b2,
                                                float* __restrict__ part,
                                                float* __restrict__ pmax) {
  __shared__ __align__(16) unsigned short a2s[128][64];
  __shared__ __align__(16) unsigned short w2s[128][64];
  __shared__ float sst1[128][17];
  __shared__ float sst2[128][17];
  __shared__ float smx[128][17];
  __shared__ float sb2[128];
  int tid = threadIdx.x;
  size_t base = (size_t)blockIdx.x * 128;  // 128 points = 4 centers x K=32
  for (int t = tid; t < 8192; t += 256) {
    int i = t >> 6, k = t & 63;
    float v = __bfloat162float(l2[base * 64 + t]);
    float a = fmaxf(fmaf(scale2[k], v, shift2[k]), 0.f);
    int kc = (k >> 3) ^ (i & 7);
    a2s[i][kc * 8 + (k & 7)] = f2bf(a);
  }
  for (int t = tid; t < 8192; t += 256) {
    int n = t >> 6, k = t & 63;
    int kc = (k >> 3) ^ (n & 7);
    w2s[n][kc * 8 + (k & 7)] = f2bf(W2[t]);
  }
  if (tid < 128) sb2[tid] = b2[tid];
  __syncthreads();
  int w = tid >> 6, l = tid & 63, lr = l & 15, lk = l >> 4;
  bf16x8 A[2][2];
#pragma unroll
  for (int mt = 0; mt < 2; mt++) {
    int row = (w * 2 + mt) * 16 + lr;
#pragma unroll
    for (int kb = 0; kb < 2; kb++) {
      int kc = (kb * 4 + lk) ^ (row & 7);
      A[mt][kb] = *(const bf16x8*)&a2s[row][kc * 8];
    }
  }
  f32x4 acc[2][8];
#pragma unroll
  for (int mt = 0; mt < 2; mt++)
#pragma unroll
    for (int nt = 0; nt < 8; nt++) acc[mt][nt] = f32x4{0.f, 0.f, 0.f, 0.f};
#pragma unroll
  for (int nt = 0; nt < 8; nt++) {
    int n = nt * 16 + lr;
    int kc0 = lk ^ (n & 7);
    int kc1 = (4 + lk) ^ (n & 7);
    bf16x8 B0 = *(const bf16x8*)&w2s[n][kc0 * 8];
    bf16x8 B1 = *(const bf16x8*)&w2s[n][kc1 * 8];
#pragma unroll
    for (int mt = 0; mt < 2; mt++) {
      acc[mt][nt] = __builtin_amdgcn_mfma_f32_16x16x32_bf16(A[mt][0], B0, acc[mt][nt], 0, 0, 0);
      acc[mt][nt] = __builtin_amdgcn_mfma_f32_16x16x32_bf16(A[mt][1], B1, acc[mt][nt], 0, 0, 0);
    }
  }
  int slot = w * 4 + lk;
#pragma unroll
  for (int nt = 0; nt < 8; nt++) {
    int c = nt * 16 + lr;
    float bias = sb2[c];
    float s1 = 0.f, s2 = 0.f, mx = -3.4e38f;
#pragma unroll
    for (int mt = 0; mt < 2; mt++)
#pragma unroll
      for (int r = 0; r < 4; r++) {
        float v = acc[mt][nt][r] + bias;
        s1 += v; s2 = fmaf(v, v, s2); mx = fmaxf(mx, v);
      }
    sst1[c][slot] = s1; sst2[c][slot] = s2; smx[c][slot] = mx;
  }
  __syncthreads();
  if (tid < 128) {
    int c = tid;
    float s1 = 0.f, s2 = 0.f;
#pragma unroll
    for (int t = 0; t < 16; t++) { s1 += sst1[c][t]; s2 += sst2[c][t]; }
    part[blockIdx.x * 256 + c] = s1;
    part[blockIdx.x * 256 + 128 + c] = s2;
#pragma unroll
    for (int q = 0; q < 4; q++) {
      float m = fmaxf(fmaxf(smx[c][4 * q + 0], smx[c][4 * q + 1]),
                      fmaxf(smx[c][4 * q + 2], smx[c][4 * q + 3]));
      pmax[((size_t)blockIdx.x * 4 + q) * 128 + c] = m;
    }
  }
}

// ---------------- BN3+ReLU on the 4MB max tensor, transposed write ----------
__global__ __launch_bounds__(256) void k_bn3(const float* __restrict__ pmax,
                                             const float* __restrict__ scale3,
                                             const float* __restrict__ shift3,
                                             float* __restrict__ dout) {
  __shared__ float tile[32][129];
  int tid = threadIdx.x;
  int b = blockIdx.x >> 4;
  int s0 = (blockIdx.x & 15) * 32;
  const float* src = pmax + ((size_t)b * SS + s0) * 128;
  for (int t = tid; t < 4096; t += 256) {
    int r = t >> 7, c = t & 127;
    tile[r][c] = src[r * 128 + c];
  }
  __syncthreads();
  float* dst = dout + 24576 + (size_t)b * 128 * SS;
  for (int t = tid; t < 4096; t += 256) {
    int c = t >> 5, r = t & 31;
    float v = tile[r][c];
    dst[(size_t)c * SS + s0 + r] = fmaxf(fmaf(scale3[c], v, shift3[c]), 0.f);
  }
}

extern "C" void kernel_launch(void* const* d_in, const int* in_sizes, int n_in,
                              void* d_out, int out_size, void* d_ws, size_t ws_size,
                              hipStream_t stream) {
  const float* xyz = (const float*)d_in[0];
  const float* pts = (const float*)d_in[1];
  const float* W0 = (const float*)d_in[2];
  const float* b0 = (const float*)d_in[3];
  const float* g0 = (const float*)d_in[4];
  const float* be0 = (const float*)d_in[5];
  const float* W1 = (const float*)d_in[6];
  const float* b1 = (const float*)d_in[7];
  const float* g1 = (const float*)d_in[8];
  const float* be1 = (const float*)d_in[9];
  const float* W2 = (const float*)d_in[10];
  const float* b2 = (const float*)d_in[11];
  const float* g2 = (const float*)d_in[12];
  const float* be2 = (const float*)d_in[13];
  float* out = (float*)d_out;

  char* ws = (char*)d_ws;
  int* gi = (int*)(ws + 32768);                              // 262144 ints
  float* newxyz = (float*)(ws + 1081344);                    // 24576 f
  float* h0 = (float*)(ws + 1179648);                        // 1572864 f (dead after k_l2)
  float* pmax = h0;                                          // 1048576 f, reuses h0 region
  float* part = (float*)(ws + 7471104);                      // 524288 f
  float* scale1 = (float*)(ws + 9568256);
  float* shift1 = scale1 + 128;
  float* scale2 = shift1 + 128;
  float* shift2 = scale2 + 128;
  float* scale3 = shift2 + 128;
  float* shift3 = scale3 + 128;
  __hip_bfloat16* l2 = (__hip_bfloat16*)(ws + 9571328);      // 16777216 bf16

  k_fps<<<BB, FT, 0, stream>>>(xyz, newxyz, out);
  k_ball<<<2048, 256, 0, stream>>>(xyz, newxyz, gi);
  k_group_stats<<<1024, 256, 0, stream>>>(xyz, pts, newxyz, gi, W0, b0, h0, part);
  k_reduce<<<64, 256, 0, stream>>>(part, 1024, g0, be0, scale1, shift1);
  k_l2<<<2048, 256, 0, stream>>>(h0, W0, b0, scale1, shift1, W1, b1, l2, part);
  k_reduce<<<64, 256, 0, stream>>>(part, 2048, g1, be1, scale2, shift2);
  k_l3pass<<<2048, 256, 0, stream>>>(l2, scale2, shift2, W2, b2, part, pmax);
  k_reduce<<<128, 256, 0, stream>>>(part, 2048, g2, be2, scale3, shift3);
  k_bn3<<<256, 256, 0, stream>>>(pmax, scale3, shift3, out);
}

// Round 17
// 426.480 us; speedup vs baseline: 1.0245x; 1.0245x over previous
//
#include <hip/hip_runtime.h>
#include <hip/hip_bf16.h>

#define BB 16
#define NN 4096
#define SS 512
#define KK 32
#define CNTF 262144.0f
#define FT 256  // FPS threads per block (4 waves)
#define FP 16   // points per thread = NN/FT

typedef short bf16x8 __attribute__((ext_vector_type(8)));
typedef float f32x4 __attribute__((ext_vector_type(4)));

__device__ __forceinline__ unsigned short f2bf(float x) {
  __hip_bfloat16 h = __float2bfloat16(x);
  return *reinterpret_cast<unsigned short*>(&h);
}

// u64 max-combine with a DPP-permuted partner (VALU pipe, no LDS latency).
// 0xB1/0x4E/0x141/0x140 then 0x142 row_bcast15 + 0x143 row_bcast31:
// lanes 48-63 end with the full 64-lane max (validated R14/R15, output-0 exact).
#define DPP_COMBINE(kk, CTRL)                                                         \
  {                                                                                   \
    unsigned lo_ = (unsigned)(kk), hi_ = (unsigned)((kk) >> 32);                      \
    unsigned plo_ = (unsigned)__builtin_amdgcn_update_dpp(0, (int)lo_, (CTRL), 0xF, 0xF, true); \
    unsigned phi_ = (unsigned)__builtin_amdgcn_update_dpp(0, (int)hi_, (CTRL), 0xF, 0xF, true); \
    unsigned long long ok_ = ((unsigned long long)phi_ << 32) | plo_;                 \
    kk = (kk) > ok_ ? (kk) : ok_;                                                     \
  }

// ---------------- FPS (EXACT R15 code — best validated: 312 us x2) ----------
// Scalar dist loop (packed variant regressed, R16); 6x DPP all-VALU reduce;
// lane-63 winner write to parity 4-key table; ONE barrier; 3-compare key
// tournament; float4 coord broadcast. FPS structural floor: R9/R11/R13/R16
// alternatives all neutral-to-negative.
__global__ __launch_bounds__(FT) void k_fps(const float* __restrict__ xyz,
                                            float* __restrict__ newxyz,
                                            float* __restrict__ dout) {
  __shared__ __align__(16) float4 ps[NN];
  __shared__ __align__(16) unsigned long long sKey[2][4];
  const int b = blockIdx.x;
  const int tid = threadIdx.x;
  const int wid = tid >> 6;
  const float* px = xyz + (size_t)b * 3 * NN;
  float lx[FP], ly[FP], lz[FP], dist[FP];
#pragma unroll
  for (int j = 0; j < FP; j++) {
    int n = j * FT + tid;
    float x = px[n], y = px[NN + n], z = px[2 * NN + n];
    lx[j] = x; ly[j] = y; lz[j] = z;
    ps[n] = make_float4(x, y, z, 0.f);
    dist[j] = 1e10f;
  }
  __syncthreads();
  float cx = px[0], cy = px[NN], cz = px[2 * NN];
  float c0x = 0.f, c0y = 0.f, c0z = 0.f, c1x = 0.f, c1y = 0.f, c1z = 0.f;
  for (int s = 0;; s++) {
    bool cap = (tid == (s & 255));
    if (s < 256) {
      if (cap) { c0x = cx; c0y = cy; c0z = cz; }
    } else {
      if (cap) { c1x = cx; c1y = cy; c1z = cz; }
    }
    if (s == SS - 1) break;
    float bestd = -1.0f;
    unsigned bestn = 0u;
#pragma unroll
    for (int j = 0; j < FP; j++) {
      // replicate ref: d = ((dx*dx + dy*dy) + dz*dz), no FMA contraction
      float dx = __fsub_rn(lx[j], cx);
      float dy = __fsub_rn(ly[j], cy);
      float dz = __fsub_rn(lz[j], cz);
      float d = __fadd_rn(__fadd_rn(__fmul_rn(dx, dx), __fmul_rn(dy, dy)), __fmul_rn(dz, dz));
      float dm = fminf(dist[j], d);
      dist[j] = dm;
      if (dm > bestd) { bestd = dm; bestn = (unsigned)(j * FT + tid); }
    }
    unsigned long long wbest =
        ((unsigned long long)__float_as_uint(bestd) << 32) | (unsigned)(~bestn);
    DPP_COMBINE(wbest, 0xB1);
    DPP_COMBINE(wbest, 0x4E);
    DPP_COMBINE(wbest, 0x141);
    DPP_COMBINE(wbest, 0x140);
    DPP_COMBINE(wbest, 0x142);
    DPP_COMBINE(wbest, 0x143);
    int p = s & 1;
    if ((tid & 63) == 63) sKey[p][wid] = wbest;
    __syncthreads();
    const ulonglong2* kp = (const ulonglong2*)&sKey[p][0];
    ulonglong2 v0 = kp[0], v1 = kp[1];
    unsigned long long ka = (v0.y > v0.x) ? v0.y : v0.x;
    unsigned long long kb = (v1.y > v1.x) ? v1.y : v1.x;
    unsigned long long km = (kb > ka) ? kb : ka;
    unsigned n = ~(unsigned)km;
    float4 c4 = ps[n];
    cx = c4.x; cy = c4.y; cz = c4.z;
  }
  {
    float* nx0 = newxyz + ((size_t)b * SS + tid) * 3;
    nx0[0] = c0x; nx0[1] = c0y; nx0[2] = c0z;
    float* nx1 = newxyz + ((size_t)b * SS + 256 + tid) * 3;
    nx1[0] = c1x; nx1[1] = c1y; nx1[2] = c1z;
    float* d0 = dout + (size_t)b * 3 * SS;
    d0[tid] = c0x;        d0[SS + tid] = c0y;        d0[2 * SS + tid] = c0z;
    d0[256 + tid] = c1x;  d0[SS + 256 + tid] = c1y;  d0[2 * SS + 256 + tid] = c1z;
  }
}

// ---------------- Ball query: one wave per center, f64 distance ----------------
__global__ __launch_bounds__(256) void k_ball(const float* __restrict__ xyz,
                                              const float* __restrict__ newxyz,
                                              int* __restrict__ gi) {
  const int lane = threadIdx.x & 63;
  const int w = threadIdx.x >> 6;
  const int idx = blockIdx.x * 4 + w;  // center id in [0, B*S)
  const int b = idx >> 9;
  const float* px = xyz + (size_t)b * 3 * NN;
  const float* c = newxyz + (size_t)idx * 3;
  const double R2 = 0.2 * 0.2;
  double cx = (double)c[0], cy = (double)c[1], cz = (double)c[2];
  double ca = cx * cx + cy * cy + cz * cz;
  int total = 0;
  int first_n = 0;
  bool found = false;
  unsigned long long lt = (1ull << lane) - 1ull;
  for (int chunk = 0; chunk < NN / 64; chunk++) {
    int n = chunk * 64 + lane;
    double x = (double)px[n], y = (double)px[NN + n], z = (double)px[2 * NN + n];
    double sb = x * x + y * y + z * z;
    double dot = cx * x + cy * y + cz * z;
    double sqr = (ca + sb) - 2.0 * dot;
    bool in = sqr <= R2;
    unsigned long long m = __ballot(in);
    if (!found && m) { first_n = chunk * 64 + __builtin_ctzll(m); found = true; }
    int rank = total + __popcll(m & lt);
    if (in && rank < KK) gi[(size_t)idx * KK + rank] = n;
    total += __popcll(m);
    if (total >= KK) break;
  }
  if (total < KK) {
    for (int slot = total + lane; slot < KK; slot += 64) gi[(size_t)idx * KK + slot] = first_n;
  }
}

// ---------------- Fused grouping + layer-1 stats (validated R15) ------------
__global__ __launch_bounds__(256) void k_group_stats(const float* __restrict__ xyz,
                                                     const float* __restrict__ pts,
                                                     const float* __restrict__ newxyz,
                                                     const int* __restrict__ gi,
                                                     const float* __restrict__ W0,
                                                     const float* __restrict__ b0,
                                                     float* __restrict__ h0,
                                                     float* __restrict__ part) {
  __shared__ float hs[256 * 6];
  __shared__ float sred[512];
  int tid = threadIdx.x;
  int base = blockIdx.x * 256;
  int m = base + tid;
  int b = m >> 14;
  int bs = m >> 5;
  int n = gi[m];
  const float* px = xyz + (size_t)b * 3 * NN;
  const float* pp = pts + (size_t)b * 3 * NN;
  const float* c = newxyz + (size_t)bs * 3;
  float f0 = px[n] - c[0];
  float f1 = px[NN + n] - c[1];
  float f2 = px[2 * NN + n] - c[2];
  float f3 = pp[n];
  float f4 = pp[NN + n];
  float f5 = pp[2 * NN + n];
  float* o = h0 + (size_t)m * 6;
  o[0] = f0; o[1] = f1; o[2] = f2; o[3] = f3; o[4] = f4; o[5] = f5;
  float* hr = hs + tid * 6;
  hr[0] = f0; hr[1] = f1; hr[2] = f2; hr[3] = f3; hr[4] = f4; hr[5] = f5;
  __syncthreads();
  int cc = tid & 63, g = tid >> 6;
  float w[6];
#pragma unroll
  for (int j = 0; j < 6; j++) w[j] = W0[cc * 6 + j];
  float bb = b0[cc];
  float s1 = 0.f, s2 = 0.f;
  for (int i = g; i < 256; i += 4) {
    float v = bb;
#pragma unroll
    for (int j = 0; j < 6; j++) v = fmaf(w[j], hs[i * 6 + j], v);
    s1 += v; s2 = fmaf(v, v, s2);
  }
  sred[tid] = s1; sred[256 + tid] = s2;
  __syncthreads();
  if (tid < 64) {
    float a = 0.f, q = 0.f;
#pragma unroll
    for (int g2 = 0; g2 < 4; g2++) { a += sred[tid + 64 * g2]; q += sred[256 + tid + 64 * g2]; }
    part[blockIdx.x * 256 + tid] = a;
    part[blockIdx.x * 256 + 128 + tid] = q;
  }
}

// ---------------- Reduce stats -> scale/shift ----------------
__global__ __launch_bounds__(256) void k_reduce(const float* __restrict__ part, int NBLK,
                                                const float* __restrict__ gamma,
                                                const float* __restrict__ beta,
                                                float* __restrict__ scale,
                                                float* __restrict__ shift) {
  __shared__ float sr[512];
  int c = blockIdx.x;
  int tid = threadIdx.x;
  float s1 = 0.f, s2 = 0.f;
  for (int nb = tid; nb < NBLK; nb += 256) {
    s1 += part[(size_t)nb * 256 + c];
    s2 += part[(size_t)nb * 256 + 128 + c];
  }
  sr[tid] = s1; sr[256 + tid] = s2;
  __syncthreads();
  for (int off = 128; off >= 1; off >>= 1) {
    if (tid < off) { sr[tid] += sr[tid + off]; sr[256 + tid] += sr[256 + tid + off]; }
    __syncthreads();
  }
  if (tid == 0) {
    float m = sr[0] / CNTF;
    float v = sr[256] / CNTF - m * m;
    float sc = gamma[c] / sqrtf(v + 1e-5f);
    scale[c] = sc;
    shift[c] = beta[c] - m * sc;
  }
}

// ---------------- Layer-2 via MFMA (validated R15) ----------
__global__ __launch_bounds__(256) void k_l2(const float* __restrict__ h0,
                                            const float* __restrict__ W0,
                                            const float* __restrict__ b0,
                                            const float* __restrict__ scale1,
                                            const float* __restrict__ shift1,
                                            const float* __restrict__ W1,
                                            const float* __restrict__ b1,
                                            __hip_bfloat16* __restrict__ l2,
                                            float* __restrict__ part) {
  __shared__ float hs[128 * 6];
  __shared__ __align__(16) unsigned short a1s[128][64];
  __shared__ __align__(16) unsigned short w1s[64][64];
  __shared__ float sst1[64][17];
  __shared__ float sst2[64][17];
  __shared__ float sb1[64];
  int tid = threadIdx.x;
  int base = blockIdx.x * 128;
  for (int t = tid; t < 768; t += 256) hs[t] = h0[(size_t)base * 6 + t];
  for (int t = tid; t < 4096; t += 256) {
    int n = t >> 6, k = t & 63;
    int kc = (k >> 3) ^ (n & 7);
    w1s[n][kc * 8 + (k & 7)] = f2bf(W1[t]);
  }
  if (tid < 64) sb1[tid] = b1[tid];
  __syncthreads();
  for (int t = tid; t < 8192; t += 256) {
    int i = t >> 6, k = t & 63;
    float v = b0[k];
#pragma unroll
    for (int j = 0; j < 6; j++) v = fmaf(W0[k * 6 + j], hs[i * 6 + j], v);
    float a = fmaxf(fmaf(scale1[k], v, shift1[k]), 0.f);
    int kc = (k >> 3) ^ (i & 7);
    a1s[i][kc * 8 + (k & 7)] = f2bf(a);
  }
  __syncthreads();
  int w = tid >> 6, l = tid & 63, lr = l & 15, lk = l >> 4;
  bf16x8 A[2][2];
#pragma unroll
  for (int mt = 0; mt < 2; mt++) {
    int row = (w * 2 + mt) * 16 + lr;
#pragma unroll
    for (int kb = 0; kb < 2; kb++) {
      int kc = (kb * 4 + lk) ^ (row & 7);
      A[mt][kb] = *(const bf16x8*)&a1s[row][kc * 8];
    }
  }
  f32x4 acc[2][4];
#pragma unroll
  for (int mt = 0; mt < 2; mt++)
#pragma unroll
    for (int nt = 0; nt < 4; nt++) acc[mt][nt] = f32x4{0.f, 0.f, 0.f, 0.f};
#pragma unroll
  for (int nt = 0; nt < 4; nt++) {
    int n = nt * 16 + lr;
    int kc0 = lk ^ (n & 7);
    int kc1 = (4 + lk) ^ (n & 7);
    bf16x8 B0 = *(const bf16x8*)&w1s[n][kc0 * 8];
    bf16x8 B1 = *(const bf16x8*)&w1s[n][kc1 * 8];
#pragma unroll
    for (int mt = 0; mt < 2; mt++) {
      acc[mt][nt] = __builtin_amdgcn_mfma_f32_16x16x32_bf16(A[mt][0], B0, acc[mt][nt], 0, 0, 0);
      acc[mt][nt] = __builtin_amdgcn_mfma_f32_16x16x32_bf16(A[mt][1], B1, acc[mt][nt], 0, 0, 0);
    }
  }
  int slot = w * 4 + lk;
#pragma unroll
  for (int nt = 0; nt < 4; nt++) {
    int cch = nt * 16 + lr;
    float bias = sb1[cch];
    float s1 = 0.f, s2 = 0.f;
#pragma unroll
    for (int mt = 0; mt < 2; mt++)
#pragma unroll
      for (int r = 0; r < 4; r++) {
        float v = acc[mt][nt][r] + bias;
        int row = (w * 2 + mt) * 16 + lk * 4 + r;  // C layout: row=(l>>4)*4+r, col=l&15
        l2[(size_t)(base + row) * 64 + cch] = __float2bfloat16(v);
        s1 += v; s2 = fmaf(v, v, s2);
      }
    sst1[cch][slot] = s1; sst2[cch][slot] = s2;
  }
  __syncthreads();
  if (tid < 64) {
    float s1 = 0.f, s2 = 0.f;
#pragma unroll
    for (int t = 0; t < 16; t++) { s1 += sst1[tid][t]; s2 += sst2[tid][t]; }
    part[blockIdx.x * 256 + tid] = s1;
    part[blockIdx.x * 256 + 128 + tid] = s2;
  }
}

// ---------------- Layer-3 single pass via MFMA (validated R11/R12) ----------
__global__ __launch_bounds__(256) void k_l3pass(const __hip_bfloat16* __restrict__ l2,
                                                const float* __restrict__ scale2,
                                                const float* __restrict__ shift2,
                                                const float* __restrict__ W2,
                                                const float* __restrict__ b2,
                                                float* __restrict__ part,
                                                float* __restrict__ pmax) {
  __shared__ __align__(16) unsigned short a2s[128][64];
  __shared__ __align__(16) unsigned short w2s[128][64];
  __shared__ float sst1[128][17];
  __shared__ float sst2[128][17];
  __shared__ float smx[128][17];
  __shared__ float sb2[128];
  int tid = threadIdx.x;
  size_t base = (size_t)blockIdx.x * 128;  // 128 points = 4 centers x K=32
  for (int t = tid; t < 8192; t += 256) {
    int i = t >> 6, k = t & 63;
    float v = __bfloat162float(l2[base * 64 + t]);
    float a = fmaxf(fmaf(scale2[k], v, shift2[k]), 0.f);
    int kc = (k >> 3) ^ (i & 7);
    a2s[i][kc * 8 + (k & 7)] = f2bf(a);
  }
  for (int t = tid; t < 8192; t += 256) {
    int n = t >> 6, k = t & 63;
    int kc = (k >> 3) ^ (n & 7);
    w2s[n][kc * 8 + (k & 7)] = f2bf(W2[t]);
  }
  if (tid < 128) sb2[tid] = b2[tid];
  __syncthreads();
  int w = tid >> 6, l = tid & 63, lr = l & 15, lk = l >> 4;
  bf16x8 A[2][2];
#pragma unroll
  for (int mt = 0; mt < 2; mt++) {
    int row = (w * 2 + mt) * 16 + lr;
#pragma unroll
    for (int kb = 0; kb < 2; kb++) {
      int kc = (kb * 4 + lk) ^ (row & 7);
      A[mt][kb] = *(const bf16x8*)&a2s[row][kc * 8];
    }
  }
  f32x4 acc[2][8];
#pragma unroll
  for (int mt = 0; mt < 2; mt++)
#pragma unroll
    for (int nt = 0; nt < 8; nt++) acc[mt][nt] = f32x4{0.f, 0.f, 0.f, 0.f};
#pragma unroll
  for (int nt = 0; nt < 8; nt++) {
    int n = nt * 16 + lr;
    int kc0 = lk ^ (n & 7);
    int kc1 = (4 + lk) ^ (n & 7);
    bf16x8 B0 = *(const bf16x8*)&w2s[n][kc0 * 8];
    bf16x8 B1 = *(const bf16x8*)&w2s[n][kc1 * 8];
#pragma unroll
    for (int mt = 0; mt < 2; mt++) {
      acc[mt][nt] = __builtin_amdgcn_mfma_f32_16x16x32_bf16(A[mt][0], B0, acc[mt][nt], 0, 0, 0);
      acc[mt][nt] = __builtin_amdgcn_mfma_f32_16x16x32_bf16(A[mt][1], B1, acc[mt][nt], 0, 0, 0);
    }
  }
  int slot = w * 4 + lk;
#pragma unroll
  for (int nt = 0; nt < 8; nt++) {
    int c = nt * 16 + lr;
    float bias = sb2[c];
    float s1 = 0.f, s2 = 0.f, mx = -3.4e38f;
#pragma unroll
    for (int mt = 0; mt < 2; mt++)
#pragma unroll
      for (int r = 0; r < 4; r++) {
        float v = acc[mt][nt][r] + bias;
        s1 += v; s2 = fmaf(v, v, s2); mx = fmaxf(mx, v);
      }
    sst1[c][slot] = s1; sst2[c][slot] = s2; smx[c][slot] = mx;
  }
  __syncthreads();
  if (tid < 128) {
    int c = tid;
    float s1 = 0.f, s2 = 0.f;
#pragma unroll
    for (int t = 0; t < 16; t++) { s1 += sst1[c][t]; s2 += sst2[c][t]; }
    part[blockIdx.x * 256 + c] = s1;
    part[blockIdx.x * 256 + 128 + c] = s2;
#pragma unroll
    for (int q = 0; q < 4; q++) {
      float m = fmaxf(fmaxf(smx[c][4 * q + 0], smx[c][4 * q + 1]),
                      fmaxf(smx[c][4 * q + 2], smx[c][4 * q + 3]));
      pmax[((size_t)blockIdx.x * 4 + q) * 128 + c] = m;
    }
  }
}

// ---------------- BN3+ReLU on the 4MB max tensor, transposed write ----------
__global__ __launch_bounds__(256) void k_bn3(const float* __restrict__ pmax,
                                             const float* __restrict__ scale3,
                                             const float* __restrict__ shift3,
                                             float* __restrict__ dout) {
  __shared__ float tile[32][129];
  int tid = threadIdx.x;
  int b = blockIdx.x >> 4;
  int s0 = (blockIdx.x & 15) * 32;
  const float* src = pmax + ((size_t)b * SS + s0) * 128;
  for (int t = tid; t < 4096; t += 256) {
    int r = t >> 7, c = t & 127;
    tile[r][c] = src[r * 128 + c];
  }
  __syncthreads();
  float* dst = dout + 24576 + (size_t)b * 128 * SS;
  for (int t = tid; t < 4096; t += 256) {
    int c = t >> 5, r = t & 31;
    float v = tile[r][c];
    dst[(size_t)c * SS + s0 + r] = fmaxf(fmaf(scale3[c], v, shift3[c]), 0.f);
  }
}

extern "C" void kernel_launch(void* const* d_in, const int* in_sizes, int n_in,
                              void* d_out, int out_size, void* d_ws, size_t ws_size,
                              hipStream_t stream) {
  const float* xyz = (const float*)d_in[0];
  const float* pts = (const float*)d_in[1];
  const float* W0 = (const float*)d_in[2];
  const float* b0 = (const float*)d_in[3];
  const float* g0 = (const float*)d_in[4];
  const float* be0 = (const float*)d_in[5];
  const float* W1 = (const float*)d_in[6];
  const float* b1 = (const float*)d_in[7];
  const float* g1 = (const float*)d_in[8];
  const float* be1 = (const float*)d_in[9];
  const float* W2 = (const float*)d_in[10];
  const float* b2 = (const float*)d_in[11];
  const float* g2 = (const float*)d_in[12];
  const float* be2 = (const float*)d_in[13];
  float* out = (float*)d_out;

  char* ws = (char*)d_ws;
  int* gi = (int*)(ws + 32768);                              // 262144 ints
  float* newxyz = (float*)(ws + 1081344);                    // 24576 f
  float* h0 = (float*)(ws + 1179648);                        // 1572864 f (dead after k_l2)
  float* pmax = h0;                                          // 1048576 f, reuses h0 region
  float* part = (float*)(ws + 7471104);                      // 524288 f
  float* scale1 = (float*)(ws + 9568256);
  float* shift1 = scale1 + 128;
  float* scale2 = shift1 + 128;
  float* shift2 = scale2 + 128;
  float* scale3 = shift2 + 128;
  float* shift3 = scale3 + 128;
  __hip_bfloat16* l2 = (__hip_bfloat16*)(ws + 9571328);      // 16777216 bf16

  k_fps<<<BB, FT, 0, stream>>>(xyz, newxyz, out);
  k_ball<<<2048, 256, 0, stream>>>(xyz, newxyz, gi);
  k_group_stats<<<1024, 256, 0, stream>>>(xyz, pts, newxyz, gi, W0, b0, h0, part);
  k_reduce<<<64, 256, 0, stream>>>(part, 1024, g0, be0, scale1, shift1);
  k_l2<<<2048, 256, 0, stream>>>(h0, W0, b0, scale1, shift1, W1, b1, l2, part);
  k_reduce<<<64, 256, 0, stream>>>(part, 2048, g1, be1, scale2, shift2);
  k_l3pass<<<2048, 256, 0, stream>>>(l2, scale2, shift2, W2, b2, part, pmax);
  k_reduce<<<128, 256, 0, stream>>>(part, 2048, g2, be2, scale3, shift3);
  k_bn3<<<256, 256, 0, stream>>>(pmax, scale3, shift3, out);
}